// Round 2
// baseline (907.205 us; speedup 1.0000x reference)
//
#include <hip/hip_runtime.h>
#include <cstddef>

// SPDRectified: out = U clamp(S, eps) U^T for 16384 symmetric 64x64 fp32
// matrices, via matrix-sign Newton-Schulz on bf16 matrix cores
// (2-word hi/lo split, 3-term products, fp32 accum).
//
// Round-2 changes vs the 580 us version (SQ_LDS_BANK_CONFLICT = 1.049e8):
//  * Tile stores: permlane32_swap fuses the two half-wave 4-row chunks
//    (same column, rows +-4) into 8 consecutive rows per lane -> one
//    b128 write at an 8-short-aligned swizzled address = same bank
//    structure as the (conflict-free) frag reads. The old b64 writes had
//    rb^swz = 0 mod 8 shorts -> only banks {4k,4k+1} -> 4-way conflict;
//    that was ~100% of the 1.05e8 conflict cycles.
//  * 2 LDS pairs (32 KB) instead of 3: Y0 dropped. Last cubic stores
//    M = (I+S)/2; final is out = X*M with X A-frags re-read from global
//    (block's own 16 KB slice, L2/L3-resident).
//  * W overwrites Y in place (all Y reads held in regs before the prior
//    barrier); Ynew overwrites Z -> 3 barriers/quintic, 2/cubic.
//  * Diag waves (wr==wc) reuse A-frags as B-frags (-20% LDS reads).

#define QA 3.4445f
#define QB (-4.7750f)
#define QC 2.0315f

using bf16x8 = __attribute__((ext_vector_type(8))) __bf16;
using f32x16 = __attribute__((ext_vector_type(16))) float;
using u32x4  = __attribute__((ext_vector_type(4))) unsigned int;
using u32x2  = __attribute__((ext_vector_type(2))) unsigned int;

__device__ __forceinline__ unsigned short f2bf(float f) {   // RNE
    unsigned u = __float_as_uint(f);
    u += 0x7FFFu + ((u >> 16) & 1u);
    return (unsigned short)(u >> 16);
}
__device__ __forceinline__ float bf2f(unsigned short h) {
    return __uint_as_float(((unsigned)h) << 16);
}
// split pair of f32 into packed-bf16 hi dword + lo dword
__device__ __forceinline__ void split2(float x0, float x1, unsigned& h, unsigned& l) {
    const unsigned short h0 = f2bf(x0), h1 = f2bf(x1);
    const unsigned short l0 = f2bf(x0 - bf2f(h0)), l1 = f2bf(x1 - bf2f(h1));
    h = (unsigned)h0 | ((unsigned)h1 << 16);
    l = (unsigned)l0 | ((unsigned)l1 << 16);
}

struct Frags { u32x4 h[4]; u32x4 l[4]; };

__device__ __forceinline__ bf16x8 asbf(u32x4 v) { return __builtin_bit_cast(bf16x8, v); }

// Frag load: row = rowbase + (lane&31), k = 16s + 8*(lane>>5) + [0..8).
// One ds_read_b128 per frag; start word = 4*(2s ^ (r&7)) -> all 32 banks
// covered per 8 lanes (conflict-free, verified round 1).
__device__ __forceinline__ void load_frags(Frags& f, const unsigned short* bh,
                                           const unsigned short* bl,
                                           int rowbase, int lane) {
    const int r   = rowbase + (lane & 31);
    const int kb  = (lane >> 5) << 3;
    const int swz = (r & 7) << 3;
    const unsigned short* ph = bh + r * 64;
    const unsigned short* pl = bl + r * 64;
#pragma unroll
    for (int s = 0; s < 4; ++s) {
        const int e = (kb + 16 * s) ^ swz;
        f.h[s] = *reinterpret_cast<const u32x4*>(ph + e);
        f.l[s] = *reinterpret_cast<const u32x4*>(pl + e);
    }
}

// 3-term compensated product: acc = Ah*Bh + Ah*Bl + Al*Bh (fp32 accum).
__device__ __forceinline__ f32x16 mm12(const Frags& A, const Frags& B) {
    f32x16 acc = {};
    __builtin_amdgcn_s_setprio(1);
#pragma unroll
    for (int s = 0; s < 4; ++s)
        acc = __builtin_amdgcn_mfma_f32_32x32x16_bf16(asbf(A.h[s]), asbf(B.h[s]), acc, 0, 0, 0);
#pragma unroll
    for (int s = 0; s < 4; ++s)
        acc = __builtin_amdgcn_mfma_f32_32x32x16_bf16(asbf(A.h[s]), asbf(B.l[s]), acc, 0, 0, 0);
#pragma unroll
    for (int s = 0; s < 4; ++s)
        acc = __builtin_amdgcn_mfma_f32_32x32x16_bf16(asbf(A.l[s]), asbf(B.h[s]), acc, 0, 0, 0);
    __builtin_amdgcn_s_setprio(0);
    return acc;
}

// C layout: col = lane&31, row = (reg&3) + 8*(reg>>2) + 4*(lane>>5).
// permlane32_swap (vdst.hi <-> vsrc.lo) pairs groups (2p, 2p+1):
//   low lanes end with rows 16p+0..7, high lanes rows 16p+8..15 of their
//   column -> one b128 write each at (rb ^ swz), rb = 32wr+16p+8hi.
__device__ __forceinline__ void store_tile2(unsigned short* bh, unsigned short* bl,
                                            const f32x16& c, int wr, int wc, int lane) {
    const int col = 32 * wc + (lane & 31);
    const int swz = (col & 7) << 3;
    const int hi  = lane >> 5;
    unsigned short* ph = bh + col * 64;
    unsigned short* pl = bl + col * 64;
#pragma unroll
    for (int p = 0; p < 2; ++p) {
        unsigned ah0, ah1, al0, al1, bh0, bh1, bl0, bl1;
        split2(c[8*p+0], c[8*p+1], ah0, al0);
        split2(c[8*p+2], c[8*p+3], ah1, al1);
        split2(c[8*p+4], c[8*p+5], bh0, bl0);
        split2(c[8*p+6], c[8*p+7], bh1, bl1);
        const u32x2 s0 = __builtin_amdgcn_permlane32_swap(ah0, bh0, false, false);
        const u32x2 s1 = __builtin_amdgcn_permlane32_swap(ah1, bh1, false, false);
        const u32x2 t0 = __builtin_amdgcn_permlane32_swap(al0, bl0, false, false);
        const u32x2 t1 = __builtin_amdgcn_permlane32_swap(al1, bl1, false, false);
        const int e = (32 * wr + 16 * p + 8 * hi) ^ swz;
        const u32x4 hv = { s0[0], s1[0], s0[1], s1[1] };
        const u32x4 lv = { t0[0], t1[0], t0[1], t1[1] };
        *reinterpret_cast<u32x4*>(ph + e) = hv;
        *reinterpret_cast<u32x4*>(pl + e) = lv;
    }
}

__global__ __launch_bounds__(256, 4)
void spd_rectified_kernel(const float* __restrict__ Xg_all,
                          float* __restrict__ out_all) {
    // 2 hi/lo buffer pairs = 32 KB -> 5 blocks/CU (LDS-wise).
    __shared__ u32x4 smem[2048];
    unsigned short* const B0h = reinterpret_cast<unsigned short*>(smem);
    unsigned short* const B0l = B0h + 4096;
    unsigned short* const B1h = B0h + 8192;
    unsigned short* const B1l = B0h + 12288;

    const int tid  = threadIdx.x;
    const int lane = tid & 63;
    const int w    = tid >> 6;
    const int wr   = w >> 1;
    const int wc   = w & 1;
    const int cl   = lane & 31;
    const int hi   = lane >> 5;
    const int hh   = hi << 2;

    const float* __restrict__ Xg = Xg_all + (size_t)blockIdx.x * 4096;
    float* __restrict__ Og = out_all + (size_t)blockIdx.x * 4096;

    // ---- load X, Frobenius^2 ----
    float4 v[4];
    float ss = 0.f;
#pragma unroll
    for (int q = 0; q < 4; ++q) {
        v[q] = reinterpret_cast<const float4*>(Xg)[q * 256 + tid];
        ss += v[q].x * v[q].x + v[q].y * v[q].y + v[q].z * v[q].z + v[q].w * v[q].w;
    }
#pragma unroll
    for (int off = 32; off > 0; off >>= 1) ss += __shfl_down(ss, off, 64);
    float* redf = reinterpret_cast<float*>(B1h);   // scratch pair unused yet
    if (lane == 0) redf[w] = ss;
    __syncthreads();
    const float total = redf[0] + redf[1] + redf[2] + redf[3];
    const float ainv  = rsqrtf(total + 1e-30f);

    // ---- Y0 = X*ainv split into pair 0 (swizzled; 16 lanes/row cover all banks) ----
#pragma unroll
    for (int q = 0; q < 4; ++q) {
        const int idx = q * 256 + tid;
        const int r   = idx >> 4;
        const int c0  = (idx & 15) << 2;
        const int e   = r * 64 + (c0 ^ ((r & 7) << 3));
        unsigned h0, l0, h1, l1;
        split2(v[q].x * ainv, v[q].y * ainv, h0, l0);
        split2(v[q].z * ainv, v[q].w * ainv, h1, l1);
        *reinterpret_cast<u32x2*>(B0h + e) = u32x2{h0, h1};
        *reinterpret_cast<u32x2*>(B0l + e) = u32x2{l0, l1};
    }
    __syncthreads();

    unsigned short *sh = B0h, *sl = B0l, *oh = B1h, *ol = B1l;
    Frags A, B;

    // ---- 4 quintic iterations: Y <- Y*(QA*I + QB*Y^2 + QC*Y^4) ----
    for (int it = 0; it < 4; ++it) {
        load_frags(A, sh, sl, 32 * wr, lane);
        if (wr != wc) load_frags(B, sh, sl, 32 * wc, lane); else B = A;
        const f32x16 z = mm12(A, B);                 // Z = Y^2
        store_tile2(oh, ol, z, wr, wc, lane);        // Z -> other pair
        __syncthreads();
        Frags A2, B2;
        load_frags(A2, oh, ol, 32 * wr, lane);
        if (wr != wc) load_frags(B2, oh, ol, 32 * wc, lane); else B2 = A2;
        const f32x16 t = mm12(A2, B2);               // T = Z^2
        f32x16 wv;
#pragma unroll
        for (int r = 0; r < 16; ++r) {               // W = QA*I + QB*Z + QC*T
            float val = QB * z[r] + QC * t[r];
            if (wr == wc && (((r >> 2) << 3) + (r & 3) + hh) == cl) val += QA;
            wv[r] = val;
        }
        store_tile2(sh, sl, wv, wr, wc, lane);       // W over Y (Y reads all pre-bar)
        __syncthreads();
        load_frags(B, sh, sl, 32 * wc, lane);        // W frags; A still holds Y
        const f32x16 yn = mm12(A, B);                // Ynew = Y*W
        store_tile2(oh, ol, yn, wr, wc, lane);       // Ynew over Z (Z reads pre-bar)
        __syncthreads();
        unsigned short* tp;
        tp = sh; sh = oh; oh = tp;
        tp = sl; sl = ol; ol = tp;
    }

    // ---- 3 cubic iterations: Y <- Y*(1.5I - 0.5*Y^2); last stores M=(I+Y)/2 ----
    for (int it = 0; it < 3; ++it) {
        load_frags(A, sh, sl, 32 * wr, lane);
        if (wr != wc) load_frags(B, sh, sl, 32 * wc, lane); else B = A;
        const f32x16 z = mm12(A, B);
        f32x16 wv;
#pragma unroll
        for (int r = 0; r < 16; ++r) {               // W = 1.5I - 0.5Z
            float val = -0.5f * z[r];
            if (wr == wc && (((r >> 2) << 3) + (r & 3) + hh) == cl) val += 1.5f;
            wv[r] = val;
        }
        store_tile2(oh, ol, wv, wr, wc, lane);       // W -> scratch pair
        __syncthreads();
        load_frags(B, oh, ol, 32 * wc, lane);
        f32x16 yn = mm12(A, B);                      // Ynew = Y*W
        if (it == 2) {
#pragma unroll
            for (int r = 0; r < 16; ++r) {           // M = (I + S)/2
                float val = 0.5f * yn[r];
                if (wr == wc && (((r >> 2) << 3) + (r & 3) + hh) == cl) val += 0.5f;
                yn[r] = val;
            }
        }
        store_tile2(sh, sl, yn, wr, wc, lane);       // in place over Y
        __syncthreads();
    }

    // ---- final: out = X * M  (X A-frags from global, M B-frags from LDS) ----
    {
        const int r = 32 * wr + cl;
        const float* xp = Xg + r * 64 + 8 * hi;
#pragma unroll
        for (int s = 0; s < 4; ++s) {
            const float4 f0 = *reinterpret_cast<const float4*>(xp + 16 * s);
            const float4 f1 = *reinterpret_cast<const float4*>(xp + 16 * s + 4);
            unsigned h0, h1, h2, h3, l0, l1, l2, l3;
            split2(f0.x, f0.y, h0, l0);
            split2(f0.z, f0.w, h1, l1);
            split2(f1.x, f1.y, h2, l2);
            split2(f1.z, f1.w, h3, l3);
            A.h[s] = u32x4{h0, h1, h2, h3};
            A.l[s] = u32x4{l0, l1, l2, l3};
        }
        load_frags(B, sh, sl, 32 * wc, lane);
        const f32x16 c = mm12(A, B);
        const int col = 32 * wc + cl;
#pragma unroll
        for (int g = 0; g < 4; ++g)
#pragma unroll
            for (int j = 0; j < 4; ++j) {
                const int row = 32 * wr + 8 * g + j + 4 * hi;
                Og[row * 64 + col] = c[4 * g + j];
            }
    }
}

extern "C" void kernel_launch(void* const* d_in, const int* in_sizes, int n_in,
                              void* d_out, int out_size, void* d_ws, size_t ws_size,
                              hipStream_t stream) {
    const float* x = (const float*)d_in[0];
    float* out = (float*)d_out;
    const int nmat = in_sizes[0] >> 12;
    spd_rectified_kernel<<<nmat, 256, 0, stream>>>(x, out);
}

// Round 3
// 594.618 us; speedup vs baseline: 1.5257x; 1.5257x over previous
//
#include <hip/hip_runtime.h>
#include <cstddef>

// SPDRectified: out = U clamp(S, eps) U^T for 16384 symmetric 64x64 fp32
// matrices, via matrix-sign Newton-Schulz on bf16 matrix cores
// (2-word hi/lo split, 3-term products Ah*Bh + Ah*Bl + Al*Bh, fp32 accum).
//
// Round-3 = round-1 structure (580 us) + round-2's verified wins, minus its
// two regressions:
//  KEEP: permlane32_swap b128 tile stores (bank-conflict fix: 1.05e8 -> 5.1e7),
//        diag-wave frag reuse, 3-barrier quintic / 2-barrier cubic schedule.
//  REVERT: launch_bounds back to (256,3) -- (256,4)'s 128-reg cap spilled
//        ~30 regs/thread -> 1.8 GB scratch writes (WRITE_SIZE 2.06e6 KB).
//  REVERT: Y0 back in LDS (3 pairs, 48 KB). Occupancy is register-bound at
//        3 waves/EU, so 32 KB LDS bought nothing, and the final X re-read
//        missed L2/L3 (input 268 MB > 256 MB L3): +520 MB FETCH.

#define QA 3.4445f
#define QB (-4.7750f)
#define QC 2.0315f

using bf16x8 = __attribute__((ext_vector_type(8))) __bf16;
using f32x16 = __attribute__((ext_vector_type(16))) float;
using u32x4  = __attribute__((ext_vector_type(4))) unsigned int;
using u32x2  = __attribute__((ext_vector_type(2))) unsigned int;
using u16x4  = __attribute__((ext_vector_type(4))) unsigned short;

__device__ __forceinline__ float bf2f(unsigned short h) {
    return __uint_as_float(((unsigned)h) << 16);
}

// Pack two f32 into one dword of 2 bf16 (RNE) + one dword of 2 bf16 residuals
// (residual truncated: its rounding error is ~2^-18 relative, irrelevant).
__device__ __forceinline__ void split2(float x0, float x1, unsigned& h, unsigned& l) {
    const unsigned u0 = __float_as_uint(x0), u1 = __float_as_uint(x1);
    const unsigned r0 = u0 + (0x7FFFu + ((u0 >> 16) & 1u));
    const unsigned r1 = u1 + (0x7FFFu + ((u1 >> 16) & 1u));
    h = (r0 >> 16) | (r1 & 0xFFFF0000u);
    const float e0 = x0 - __uint_as_float(r0 & 0xFFFF0000u);
    const float e1 = x1 - __uint_as_float(r1 & 0xFFFF0000u);
    l = (__float_as_uint(e0) >> 16) | (__float_as_uint(e1) & 0xFFFF0000u);
}

struct Frags { u32x4 h[4]; u32x4 l[4]; };

__device__ __forceinline__ bf16x8 asbf(u32x4 v) { return __builtin_bit_cast(bf16x8, v); }

// Frag load: row = rowbase + (lane&31), k = 16s + 8*(lane>>5) + [0..8).
// One ds_read_b128 per frag; per 8-lane phase the swizzle spans all 32 banks.
__device__ __forceinline__ void load_frags(Frags& f, const unsigned short* bh,
                                           const unsigned short* bl,
                                           int rowbase, int lane) {
    const int r   = rowbase + (lane & 31);
    const int kb  = (lane >> 5) << 3;
    const int swz = (r & 7) << 3;
    const unsigned short* ph = bh + r * 64;
    const unsigned short* pl = bl + r * 64;
#pragma unroll
    for (int s = 0; s < 4; ++s) {
        const int e = (kb + 16 * s) ^ swz;
        f.h[s] = *reinterpret_cast<const u32x4*>(ph + e);
        f.l[s] = *reinterpret_cast<const u32x4*>(pl + e);
    }
}

// 3-term compensated product: acc = Ah*Bh + Ah*Bl + Al*Bh (fp32 accum).
__device__ __forceinline__ f32x16 mm12(const Frags& A, const Frags& B) {
    f32x16 acc = {};
    __builtin_amdgcn_s_setprio(1);
#pragma unroll
    for (int s = 0; s < 4; ++s)
        acc = __builtin_amdgcn_mfma_f32_32x32x16_bf16(asbf(A.h[s]), asbf(B.h[s]), acc, 0, 0, 0);
#pragma unroll
    for (int s = 0; s < 4; ++s)
        acc = __builtin_amdgcn_mfma_f32_32x32x16_bf16(asbf(A.h[s]), asbf(B.l[s]), acc, 0, 0, 0);
#pragma unroll
    for (int s = 0; s < 4; ++s)
        acc = __builtin_amdgcn_mfma_f32_32x32x16_bf16(asbf(A.l[s]), asbf(B.h[s]), acc, 0, 0, 0);
    __builtin_amdgcn_s_setprio(0);
    return acc;
}

// C layout: col = lane&31, row = (reg&3) + 8*(reg>>2) + 4*(lane>>5).
// permlane32_swap fuses the half-wave 4-row chunks into 8 consecutive rows
// per lane -> one b128 write at an 8-short-aligned swizzled address (same
// conflict-free bank structure as the frag reads).
__device__ __forceinline__ void store_tile2(unsigned short* bh, unsigned short* bl,
                                            const f32x16& c, int wr, int wc, int lane) {
    const int col = 32 * wc + (lane & 31);
    const int swz = (col & 7) << 3;
    const int hi  = lane >> 5;
    unsigned short* ph = bh + col * 64;
    unsigned short* pl = bl + col * 64;
#pragma unroll
    for (int p = 0; p < 2; ++p) {
        unsigned ah0, ah1, al0, al1, bh0, bh1, bl0, bl1;
        split2(c[8*p+0], c[8*p+1], ah0, al0);
        split2(c[8*p+2], c[8*p+3], ah1, al1);
        split2(c[8*p+4], c[8*p+5], bh0, bl0);
        split2(c[8*p+6], c[8*p+7], bh1, bl1);
        const u32x2 s0 = __builtin_amdgcn_permlane32_swap(ah0, bh0, false, false);
        const u32x2 s1 = __builtin_amdgcn_permlane32_swap(ah1, bh1, false, false);
        const u32x2 t0 = __builtin_amdgcn_permlane32_swap(al0, bl0, false, false);
        const u32x2 t1 = __builtin_amdgcn_permlane32_swap(al1, bl1, false, false);
        const int e = (32 * wr + 16 * p + 8 * hi) ^ swz;
        const u32x4 hv = { s0[0], s1[0], s0[1], s1[1] };
        const u32x4 lv = { t0[0], t1[0], t0[1], t1[1] };
        *reinterpret_cast<u32x4*>(ph + e) = hv;
        *reinterpret_cast<u32x4*>(pl + e) = lv;
    }
}

__global__ __launch_bounds__(256, 3)
void spd_rectified_kernel(const float* __restrict__ Xg_all,
                          float* __restrict__ out_all) {
    // 3 hi/lo buffer pairs = 48 KB.
    __shared__ u32x4 smem[3072];
    __shared__ float red[4];
    unsigned short* const Y0h = reinterpret_cast<unsigned short*>(smem);
    unsigned short* const Y0l = Y0h + 4096;
    unsigned short* const Bah = Y0h + 8192;
    unsigned short* const Bal = Y0h + 12288;
    unsigned short* const Bbh = Y0h + 16384;
    unsigned short* const Bbl = Y0h + 20480;

    const int tid  = threadIdx.x;
    const int lane = tid & 63;
    const int w    = tid >> 6;
    const int wr   = w >> 1;
    const int wc   = w & 1;
    const int cl   = lane & 31;
    const int hi   = lane >> 5;
    const int hh   = hi << 2;

    const float* __restrict__ Xg = Xg_all + (size_t)blockIdx.x * 4096;
    float* __restrict__ Og = out_all + (size_t)blockIdx.x * 4096;

    // ---- load X, Frobenius^2 ----
    float4 v[4];
    float ss = 0.f;
#pragma unroll
    for (int q = 0; q < 4; ++q) {
        v[q] = reinterpret_cast<const float4*>(Xg)[q * 256 + tid];
        ss += v[q].x * v[q].x + v[q].y * v[q].y + v[q].z * v[q].z + v[q].w * v[q].w;
    }
#pragma unroll
    for (int off = 32; off > 0; off >>= 1) ss += __shfl_down(ss, off, 64);
    if (lane == 0) red[w] = ss;
    __syncthreads();
    const float total = red[0] + red[1] + red[2] + red[3];
    const float ainv  = rsqrtf(total + 1e-30f);
    const float alpha = total * ainv;          // sqrt(total)

    // ---- Y0 = X*ainv split into pair 0 (swizzled) ----
#pragma unroll
    for (int q = 0; q < 4; ++q) {
        const int idx = q * 256 + tid;
        const int r   = idx >> 4;
        const int c0  = (idx & 15) << 2;
        const int e   = r * 64 + (c0 ^ ((r & 7) << 3));
        unsigned h0, l0, h1, l1;
        split2(v[q].x * ainv, v[q].y * ainv, h0, l0);
        split2(v[q].z * ainv, v[q].w * ainv, h1, l1);
        *reinterpret_cast<u32x2*>(Y0h + e) = u32x2{h0, h1};
        *reinterpret_cast<u32x2*>(Y0l + e) = u32x2{l0, l1};
    }
    __syncthreads();

    // src = Y0 for the first iteration; f1/f2 are the scratch pair-pointers.
    const unsigned short *sh = Y0h, *sl = Y0l;
    unsigned short *f1h = Bah, *f1l = Bal;
    unsigned short *f2h = Bbh, *f2l = Bbl;
    Frags A, B;

    // ---- 4 quintic iterations: Y <- Y*(QA*I + QB*Y^2 + QC*Y^4) ----
    for (int it = 0; it < 4; ++it) {
        load_frags(A, sh, sl, 32 * wr, lane);
        if (wr != wc) load_frags(B, sh, sl, 32 * wc, lane); else B = A;
        const f32x16 z = mm12(A, B);                 // Z = Y^2
        store_tile2(f1h, f1l, z, wr, wc, lane);      // Z -> f1
        __syncthreads();
        Frags A2, B2;
        load_frags(A2, f1h, f1l, 32 * wr, lane);
        if (wr != wc) load_frags(B2, f1h, f1l, 32 * wc, lane); else B2 = A2;
        const f32x16 t = mm12(A2, B2);               // T = Z^2
        f32x16 wv;
#pragma unroll
        for (int r = 0; r < 16; ++r) {               // W = QA*I + QB*Z + QC*T
            float val = QB * z[r] + QC * t[r];
            if (wr == wc && (((r >> 2) << 3) + (r & 3) + hh) == cl) val += QA;
            wv[r] = val;
        }
        // W dest: first iter must preserve Y0 -> f2; later iters overwrite src
        // (all src frag reads happened before the barrier above).
        unsigned short* dwh = (it == 0) ? f2h : const_cast<unsigned short*>(sh);
        unsigned short* dwl = (it == 0) ? f2l : const_cast<unsigned short*>(sl);
        store_tile2(dwh, dwl, wv, wr, wc, lane);
        __syncthreads();
        load_frags(B, dwh, dwl, 32 * wc, lane);      // W frags; A still holds Y
        const f32x16 yn = mm12(A, B);                // Ynew = Y*W
        store_tile2(f1h, f1l, yn, wr, wc, lane);     // over Z (reads done pre-bar)
        __syncthreads();
        // rotate: new src = f1; new f1 = buffer now holding dead W
        sh = f1h; sl = f1l;
        f1h = dwh; f1l = dwl;
    }

    // ---- 3 cubic iterations: Y <- Y*(1.5I - 0.5*Y^2) ----
    for (int it = 0; it < 3; ++it) {
        load_frags(A, sh, sl, 32 * wr, lane);
        if (wr != wc) load_frags(B, sh, sl, 32 * wc, lane); else B = A;
        const f32x16 z = mm12(A, B);
        f32x16 wv;
#pragma unroll
        for (int r = 0; r < 16; ++r) {               // W = 1.5I - 0.5Z
            float val = -0.5f * z[r];
            if (wr == wc && (((r >> 2) << 3) + (r & 3) + hh) == cl) val += 1.5f;
            wv[r] = val;
        }
        store_tile2(f1h, f1l, wv, wr, wc, lane);     // W -> scratch
        __syncthreads();
        load_frags(B, f1h, f1l, 32 * wc, lane);
        const f32x16 yn = mm12(A, B);                // Ynew = Y*W
        store_tile2(const_cast<unsigned short*>(sh),
                    const_cast<unsigned short*>(sl),
                    yn, wr, wc, lane);               // in place (reads pre-bar)
        __syncthreads();
    }

    // ---- final: out = 0.5*alpha*(Y0 + Y0*S), S in src pair ----
    load_frags(A, Y0h, Y0l, 32 * wr, lane);
    load_frags(B, sh, sl, 32 * wc, lane);
    const f32x16 c = mm12(A, B);
    const float hsc = 0.5f * alpha;
    const int col = 32 * wc + cl;
    const int swz = (col & 7) << 3;
    const int rb0 = 32 * wr + hh;
#pragma unroll
    for (int g = 0; g < 4; ++g) {
        const int rb = rb0 + 8 * g;
        const int e  = col * 64 + (rb ^ swz);
        const u16x4 yh = *reinterpret_cast<const u16x4*>(Y0h + e);
        const u16x4 yl = *reinterpret_cast<const u16x4*>(Y0l + e);
#pragma unroll
        for (int j = 0; j < 4; ++j) {
            const float y0 = bf2f(yh[j]) + bf2f(yl[j]);
            Og[(rb + j) * 64 + col] = hsc * (y0 + c[4 * g + j]);
        }
    }
}

extern "C" void kernel_launch(void* const* d_in, const int* in_sizes, int n_in,
                              void* d_out, int out_size, void* d_ws, size_t ws_size,
                              hipStream_t stream) {
    const float* x = (const float*)d_in[0];
    float* out = (float*)d_out;
    const int nmat = in_sizes[0] >> 12;
    spd_rectified_kernel<<<nmat, 256, 0, stream>>>(x, out);
}

// Round 4
// 455.164 us; speedup vs baseline: 1.9931x; 1.3064x over previous
//
#include <hip/hip_runtime.h>
#include <cstddef>

// SPDRectified: out = U clamp(S,eps) U^T for 16384 symmetric 64x64 fp32
// matrices via matrix-sign Newton-Schulz (4 quintic + 3 cubic) on bf16
// matrix cores with 2-word hi/lo split (3-term products, fp32 accum).
//
// Round-4: fully register-resident, ONE WAVE PER MATRIX.
//  - The 4-wave LDS structure spent ~340 us/CU in the LDS pipe (250 us
//    minimum cycles + 90 us conflicts) plus 24 barriers of lockstep.
//  - A wave64 holds the whole matrix as MFMA A-frags (hi+lo = 128 regs).
//    The C-layout -> A-frag conversion is store_tile2's permlane32_swap
//    with the LDS round-trip deleted: acc tile (I,J), half p  ->  band-J
//    frag q=2I+p (byte-identical mapping, symmetry-exact as before).
//  - Zero __syncthreads, zero cooperative LDS. Y0 parked in LDS
//    (lane-private slots, conflict-free) to keep peak regs ~384 < 512.
//  - split2 via v_cvt_pk_bf16_f32 (6 VALU ops instead of ~12).
//  - __launch_bounds__(64,1): 1 wave/SIMD of the 512-reg unified pool.

#define QA 3.4445f
#define QB (-4.7750f)
#define QC 2.0315f

using bf16x8 = __attribute__((ext_vector_type(8))) __bf16;
using f32x16 = __attribute__((ext_vector_type(16))) float;
using u32x4  = __attribute__((ext_vector_type(4))) unsigned int;
using u32x2  = __attribute__((ext_vector_type(2))) unsigned int;

__device__ __forceinline__ bf16x8 asbf(u32x4 v) { return __builtin_bit_cast(bf16x8, v); }

// Pack two f32 -> dword of 2 bf16 (RNE) + dword of 2 bf16 residuals.
__device__ __forceinline__ void split2(float x0, float x1, unsigned& h, unsigned& l) {
    unsigned hh, ll;
    asm("v_cvt_pk_bf16_f32 %0, %1, %2" : "=v"(hh) : "v"(x0), "v"(x1));
    const float e0 = x0 - __uint_as_float(hh << 16);
    const float e1 = x1 - __uint_as_float(hh & 0xFFFF0000u);
    asm("v_cvt_pk_bf16_f32 %0, %1, %2" : "=v"(ll) : "v"(e0), "v"(e1));
    h = hh; l = ll;
}

#define MFMA_(A, B, C) __builtin_amdgcn_mfma_f32_32x32x16_bf16(asbf(A), asbf(B), C, 0, 0, 0)

// 3-term compensated 64x64 product: acc(I,J) = Ah.Bh + Ah.Bl + Al.Bh.
// B-operand = frag data of the (symmetric) B matrix, as in the LDS version.
__device__ __forceinline__ void matmul3(const u32x4 (&Ah)[2][4], const u32x4 (&Al)[2][4],
                                        const u32x4 (&Bh)[2][4], const u32x4 (&Bl)[2][4],
                                        f32x16& a00, f32x16& a01, f32x16& a10, f32x16& a11) {
    const f32x16 zz = {};
    a00 = zz; a01 = zz; a10 = zz; a11 = zz;
#pragma unroll
    for (int q = 0; q < 4; ++q) {
        a00 = MFMA_(Ah[0][q], Bh[0][q], a00);
        a01 = MFMA_(Ah[0][q], Bh[1][q], a01);
        a10 = MFMA_(Ah[1][q], Bh[0][q], a10);
        a11 = MFMA_(Ah[1][q], Bh[1][q], a11);
    }
#pragma unroll
    for (int q = 0; q < 4; ++q) {
        a00 = MFMA_(Ah[0][q], Bl[0][q], a00);
        a01 = MFMA_(Ah[0][q], Bl[1][q], a01);
        a10 = MFMA_(Ah[1][q], Bl[0][q], a10);
        a11 = MFMA_(Ah[1][q], Bl[1][q], a11);
    }
#pragma unroll
    for (int q = 0; q < 4; ++q) {
        a00 = MFMA_(Al[0][q], Bh[0][q], a00);
        a01 = MFMA_(Al[0][q], Bh[1][q], a01);
        a10 = MFMA_(Al[1][q], Bh[0][q], a10);
        a11 = MFMA_(Al[1][q], Bh[1][q], a11);
    }
}

// C-layout acc tile (I,J) -> A-frags (band J, q = 2I+p), in registers.
// Identical byte production to round-3's verified store_tile2/load_frags pair.
__device__ __forceinline__ void conv_tile(const f32x16& cc,
                                          u32x4& fh0, u32x4& fl0,
                                          u32x4& fh1, u32x4& fl1) {
#pragma unroll
    for (int p = 0; p < 2; ++p) {
        unsigned ah0, ah1, bh0, bh1, al0, al1, bl0, bl1;
        split2(cc[8*p+0], cc[8*p+1], ah0, al0);
        split2(cc[8*p+2], cc[8*p+3], ah1, al1);
        split2(cc[8*p+4], cc[8*p+5], bh0, bl0);
        split2(cc[8*p+6], cc[8*p+7], bh1, bl1);
        const u32x2 s0 = __builtin_amdgcn_permlane32_swap(ah0, bh0, false, false);
        const u32x2 s1 = __builtin_amdgcn_permlane32_swap(ah1, bh1, false, false);
        const u32x2 t0 = __builtin_amdgcn_permlane32_swap(al0, bl0, false, false);
        const u32x2 t1 = __builtin_amdgcn_permlane32_swap(al1, bl1, false, false);
        const u32x4 fh = {s0[0], s1[0], s0[1], s1[1]};
        const u32x4 fl = {t0[0], t1[0], t0[1], t1[1]};
        if (p == 0) { fh0 = fh; fl0 = fl; } else { fh1 = fh; fl1 = fl; }
    }
}

// conv all 4 acc tiles into a frag set: tile(I,J) -> [band J][q=2I+p]
#define CONV4(C00, C01, C10, C11, FH, FL)                    \
    conv_tile(C00, FH[0][0], FL[0][0], FH[0][1], FL[0][1]);  \
    conv_tile(C01, FH[1][0], FL[1][0], FH[1][1], FL[1][1]);  \
    conv_tile(C10, FH[0][2], FL[0][2], FH[0][3], FL[0][3]);  \
    conv_tile(C11, FH[1][2], FL[1][2], FH[1][3], FL[1][3]);

__global__ __launch_bounds__(64, 1)
void spd_rectified_kernel(const float* __restrict__ Xg_all,
                          float* __restrict__ out_all) {
    // Y0 parking: lane-private 16B slots, bank = (lane*4)%32 -> conflict-free.
    __shared__ u32x4 park[16][64];

    const int lane = threadIdx.x;       // 64 threads = 1 wave
    const int c    = lane & 31;
    const int hi   = lane >> 5;

    const float* __restrict__ Xg = Xg_all + (size_t)blockIdx.x * 4096;
    float* __restrict__ Og = out_all + (size_t)blockIdx.x * 4096;

    // ---- load X in frag-shaped slices: row 32b+c, k = 16q+8hi+[0,8) ----
    float4 xv[2][4][2];
    float ss = 0.f;
#pragma unroll
    for (int b = 0; b < 2; ++b) {
        const float* xr = Xg + (32*b + c) * 64 + 8*hi;
#pragma unroll
        for (int q = 0; q < 4; ++q) {
            const float4 f0 = *reinterpret_cast<const float4*>(xr + 16*q);
            const float4 f1 = *reinterpret_cast<const float4*>(xr + 16*q + 4);
            xv[b][q][0] = f0; xv[b][q][1] = f1;
            ss += f0.x*f0.x + f0.y*f0.y + f0.z*f0.z + f0.w*f0.w;
            ss += f1.x*f1.x + f1.y*f1.y + f1.z*f1.z + f1.w*f1.w;
        }
    }
#pragma unroll
    for (int off = 32; off; off >>= 1) ss += __shfl_xor(ss, off, 64);
    const float ainv  = rsqrtf(ss + 1e-30f);
    const float alpha = ss * ainv;      // sqrt(ss)

    // ---- Y0 = X*ainv as frags; keep as iterate Y, park a copy in LDS ----
    u32x4 Yh[2][4], Yl[2][4];
#pragma unroll
    for (int b = 0; b < 2; ++b)
#pragma unroll
        for (int q = 0; q < 4; ++q) {
            const float4 f0 = xv[b][q][0], f1 = xv[b][q][1];
            unsigned h0, l0, h1, l1, h2, l2, h3, l3;
            split2(f0.x*ainv, f0.y*ainv, h0, l0);
            split2(f0.z*ainv, f0.w*ainv, h1, l1);
            split2(f1.x*ainv, f1.y*ainv, h2, l2);
            split2(f1.z*ainv, f1.w*ainv, h3, l3);
            Yh[b][q] = u32x4{h0, h1, h2, h3};
            Yl[b][q] = u32x4{l0, l1, l2, l3};
            park[b*4 + q][lane]     = Yh[b][q];
            park[8 + b*4 + q][lane] = Yl[b][q];
        }

    u32x4 Gh[2][4], Gl[2][4];           // scratch frag set (Z, then W)

    // ---- 4 quintic iterations: Y <- Y*(QA*I + QB*Y^2 + QC*Y^4) ----
#pragma unroll 1
    for (int it = 0; it < 4; ++it) {
        f32x16 z00, z01, z10, z11;
        matmul3(Yh, Yl, Yh, Yl, z00, z01, z10, z11);     // Z = Y^2
        CONV4(z00, z01, z10, z11, Gh, Gl);               // Z frags (keep z accs)
        f32x16 t00, t01, t10, t11;
        matmul3(Gh, Gl, Gh, Gl, t00, t01, t10, t11);     // T = Z^2
#pragma unroll
        for (int r = 0; r < 16; ++r) {                   // W = QA*I+QB*Z+QC*T
            const int rw = (r & 3) + 8*(r >> 2) + 4*hi;
            float w;
            w = QB*z00[r] + QC*t00[r]; if (rw == c) w += QA; z00[r] = w;
            w = QB*z01[r] + QC*t01[r];                       z01[r] = w;
            w = QB*z10[r] + QC*t10[r];                       z10[r] = w;
            w = QB*z11[r] + QC*t11[r]; if (rw == c) w += QA; z11[r] = w;
        }
        CONV4(z00, z01, z10, z11, Gh, Gl);               // W frags
        f32x16 y00, y01, y10, y11;
        matmul3(Yh, Yl, Gh, Gl, y00, y01, y10, y11);     // Ynew = Y*W
        CONV4(y00, y01, y10, y11, Yh, Yl);
    }

    // ---- 3 cubic iterations: Y <- Y*(1.5I - 0.5*Y^2) ----
#pragma unroll 1
    for (int it = 0; it < 3; ++it) {
        f32x16 z00, z01, z10, z11;
        matmul3(Yh, Yl, Yh, Yl, z00, z01, z10, z11);     // Z = Y^2
#pragma unroll
        for (int r = 0; r < 16; ++r) {                   // W = 1.5I - 0.5Z
            const int rw = (r & 3) + 8*(r >> 2) + 4*hi;
            float w;
            w = -0.5f*z00[r]; if (rw == c) w += 1.5f; z00[r] = w;
            w = -0.5f*z01[r];                         z01[r] = w;
            w = -0.5f*z10[r];                         z10[r] = w;
            w = -0.5f*z11[r]; if (rw == c) w += 1.5f; z11[r] = w;
        }
        CONV4(z00, z01, z10, z11, Gh, Gl);               // W frags
        f32x16 y00, y01, y10, y11;
        matmul3(Yh, Yl, Gh, Gl, y00, y01, y10, y11);     // Ynew = Y*W
        CONV4(y00, y01, y10, y11, Yh, Yl);
    }

    // ---- final: out = 0.5*alpha*(Y0 + Y0*S), S = Y ----
    u32x4 Ph[2][4], Pl[2][4];                            // unpark Y0
#pragma unroll
    for (int b = 0; b < 2; ++b)
#pragma unroll
        for (int q = 0; q < 4; ++q) {
            Ph[b][q] = park[b*4 + q][lane];
            Pl[b][q] = park[8 + b*4 + q][lane];
        }
    f32x16 c00, c01, c10, c11;
    matmul3(Ph, Pl, Yh, Yl, c00, c01, c10, c11);         // C = Y0*S
    const float hsc = 0.5f * alpha;

    // Per tile (I,J): X values at C-layout positions come from the lane's own
    // band-J Y0 frags + the partner half via permlane32_swap(quadA, quadB):
    // result[0] serves even row-quads m, result[1] odd m.
#define FINTILE(I, J, CC)                                                       \
    {                                                                           \
        const u32x2 sA0 = __builtin_amdgcn_permlane32_swap(Ph[J][2*I][0],  Ph[J][2*I][2],  false, false); \
        const u32x2 sA1 = __builtin_amdgcn_permlane32_swap(Ph[J][2*I][1],  Ph[J][2*I][3],  false, false); \
        const u32x2 sB0 = __builtin_amdgcn_permlane32_swap(Ph[J][2*I+1][0], Ph[J][2*I+1][2], false, false); \
        const u32x2 sB1 = __builtin_amdgcn_permlane32_swap(Ph[J][2*I+1][1], Ph[J][2*I+1][3], false, false); \
        const u32x2 uA0 = __builtin_amdgcn_permlane32_swap(Pl[J][2*I][0],  Pl[J][2*I][2],  false, false); \
        const u32x2 uA1 = __builtin_amdgcn_permlane32_swap(Pl[J][2*I][1],  Pl[J][2*I][3],  false, false); \
        const u32x2 uB0 = __builtin_amdgcn_permlane32_swap(Pl[J][2*I+1][0], Pl[J][2*I+1][2], false, false); \
        const u32x2 uB1 = __builtin_amdgcn_permlane32_swap(Pl[J][2*I+1][1], Pl[J][2*I+1][3], false, false); \
        _Pragma("unroll")                                                       \
        for (int m = 0; m < 4; ++m) {                                           \
            const int sel = m & 1;                                              \
            const unsigned hd0 = (m >> 1) ? sB0[sel] : sA0[sel];                \
            const unsigned hd1 = (m >> 1) ? sB1[sel] : sA1[sel];                \
            const unsigned ld0 = (m >> 1) ? uB0[sel] : uA0[sel];                \
            const unsigned ld1 = (m >> 1) ? uB1[sel] : uA1[sel];                \
            _Pragma("unroll")                                                   \
            for (int j = 0; j < 4; ++j) {                                       \
                const unsigned hd = (j >> 1) ? hd1 : hd0;                       \
                const unsigned ld = (j >> 1) ? ld1 : ld0;                       \
                const float fh = __uint_as_float((j & 1) ? (hd & 0xFFFF0000u) : (hd << 16)); \
                const float fl = __uint_as_float((j & 1) ? (ld & 0xFFFF0000u) : (ld << 16)); \
                const float o  = hsc * ((fh + fl) + CC[4*m + j]);               \
                Og[(32*(I) + 8*m + 4*hi + j) * 64 + 32*(J) + c] = o;            \
            }                                                                   \
        }                                                                       \
    }

    FINTILE(0, 0, c00)
    FINTILE(0, 1, c01)
    FINTILE(1, 0, c10)
    FINTILE(1, 1, c11)
#undef FINTILE
}

extern "C" void kernel_launch(void* const* d_in, const int* in_sizes, int n_in,
                              void* d_out, int out_size, void* d_ws, size_t ws_size,
                              hipStream_t stream) {
    const float* x = (const float*)d_in[0];
    float* out = (float*)d_out;
    const int nmat = in_sizes[0] >> 12;
    spd_rectified_kernel<<<nmat, 64, 0, stream>>>(x, out);
}

// Round 5
// 449.756 us; speedup vs baseline: 2.0171x; 1.0120x over previous
//
#include <hip/hip_runtime.h>
#include <cstddef>

// SPDRectified: out = U clamp(S,eps) U^T for 16384 symmetric 64x64 fp32
// matrices via matrix-sign Newton-Schulz (4 quintic + 3 cubic) on bf16
// matrix cores, 2-word hi/lo split (3-term products, fp32 accum).
//
// Round-5: round-4's one-wave-per-matrix register-resident design, + 2
// waves/SIMD. Round 4 measured OccupancyPercent 11.3 (1 wave/SIMD) and a
// ~4x latency-stall factor (80k cyc/matrix vs ~20k pipe cycles). The reg
// peak was the quintic's T=Z^2 phase: Y(64)+Zfrags(64)+z-accs(64)+t(64).
// Fix: drop z-accs; reconstruct Z from its own frags at combine time --
// permlane32_swap is an involution, hi+lo unpack recovers Z to 2^-17
// (same precision the MFMAs consume, absmax unchanged). Peak ~224 regs
// -> __launch_bounds__(64,2) caps unified file at 256 -> 2 waves/SIMD.
// Tripwire: WRITE_SIZE must stay 262144 KB (else the cap spilled).

#define QA 3.4445f
#define QB (-4.7750f)
#define QC 2.0315f

using bf16x8 = __attribute__((ext_vector_type(8))) __bf16;
using f32x16 = __attribute__((ext_vector_type(16))) float;
using u32x4  = __attribute__((ext_vector_type(4))) unsigned int;
using u32x2  = __attribute__((ext_vector_type(2))) unsigned int;

__device__ __forceinline__ bf16x8 asbf(u32x4 v) { return __builtin_bit_cast(bf16x8, v); }

// Pack two f32 -> dword of 2 bf16 (RNE) + dword of 2 bf16 residuals.
__device__ __forceinline__ void split2(float x0, float x1, unsigned& h, unsigned& l) {
    unsigned hh, ll;
    asm("v_cvt_pk_bf16_f32 %0, %1, %2" : "=v"(hh) : "v"(x0), "v"(x1));
    const float e0 = x0 - __uint_as_float(hh << 16);
    const float e1 = x1 - __uint_as_float(hh & 0xFFFF0000u);
    asm("v_cvt_pk_bf16_f32 %0, %1, %2" : "=v"(ll) : "v"(e0), "v"(e1));
    h = hh; l = ll;
}

#define MFMA_(A, B, C) __builtin_amdgcn_mfma_f32_32x32x16_bf16(asbf(A), asbf(B), C, 0, 0, 0)

// 3-term compensated 64x64 product: acc(I,J) = Ah.Bh + Ah.Bl + Al.Bh.
__device__ __forceinline__ void matmul3(const u32x4 (&Ah)[2][4], const u32x4 (&Al)[2][4],
                                        const u32x4 (&Bh)[2][4], const u32x4 (&Bl)[2][4],
                                        f32x16& a00, f32x16& a01, f32x16& a10, f32x16& a11) {
    const f32x16 zz = {};
    a00 = zz; a01 = zz; a10 = zz; a11 = zz;
    __builtin_amdgcn_s_setprio(1);
#pragma unroll
    for (int q = 0; q < 4; ++q) {
        a00 = MFMA_(Ah[0][q], Bh[0][q], a00);
        a01 = MFMA_(Ah[0][q], Bh[1][q], a01);
        a10 = MFMA_(Ah[1][q], Bh[0][q], a10);
        a11 = MFMA_(Ah[1][q], Bh[1][q], a11);
    }
#pragma unroll
    for (int q = 0; q < 4; ++q) {
        a00 = MFMA_(Ah[0][q], Bl[0][q], a00);
        a01 = MFMA_(Ah[0][q], Bl[1][q], a01);
        a10 = MFMA_(Ah[1][q], Bl[0][q], a10);
        a11 = MFMA_(Ah[1][q], Bl[1][q], a11);
    }
#pragma unroll
    for (int q = 0; q < 4; ++q) {
        a00 = MFMA_(Al[0][q], Bh[0][q], a00);
        a01 = MFMA_(Al[0][q], Bh[1][q], a01);
        a10 = MFMA_(Al[1][q], Bh[0][q], a10);
        a11 = MFMA_(Al[1][q], Bh[1][q], a11);
    }
    __builtin_amdgcn_s_setprio(0);
}

// C-layout acc tile (I,J) -> A-frags (band J, q = 2I+p), in registers.
__device__ __forceinline__ void conv_tile(const f32x16& cc,
                                          u32x4& fh0, u32x4& fl0,
                                          u32x4& fh1, u32x4& fl1) {
#pragma unroll
    for (int p = 0; p < 2; ++p) {
        unsigned ah0, ah1, bh0, bh1, al0, al1, bl0, bl1;
        split2(cc[8*p+0], cc[8*p+1], ah0, al0);
        split2(cc[8*p+2], cc[8*p+3], ah1, al1);
        split2(cc[8*p+4], cc[8*p+5], bh0, bl0);
        split2(cc[8*p+6], cc[8*p+7], bh1, bl1);
        const u32x2 s0 = __builtin_amdgcn_permlane32_swap(ah0, bh0, false, false);
        const u32x2 s1 = __builtin_amdgcn_permlane32_swap(ah1, bh1, false, false);
        const u32x2 t0 = __builtin_amdgcn_permlane32_swap(al0, bl0, false, false);
        const u32x2 t1 = __builtin_amdgcn_permlane32_swap(al1, bl1, false, false);
        const u32x4 fh = {s0[0], s1[0], s0[1], s1[1]};
        const u32x4 fl = {t0[0], t1[0], t0[1], t1[1]};
        if (p == 0) { fh0 = fh; fl0 = fl; } else { fh1 = fh; fl1 = fl; }
    }
}

#define CONV4(C00, C01, C10, C11, FH, FL)                    \
    conv_tile(C00, FH[0][0], FL[0][0], FH[0][1], FL[0][1]);  \
    conv_tile(C01, FH[1][0], FL[1][0], FH[1][1], FL[1][1]);  \
    conv_tile(C10, FH[0][2], FL[0][2], FH[0][3], FL[0][3]);  \
    conv_tile(C11, FH[1][2], FL[1][2], FH[1][3], FL[1][3]);

// Inverse of conv_tile (permlane32_swap is an involution): recover tile
// (I,J)'s C-layout values from frags Gh/Gl[J][2I+p], then combine in place:
//   t[r] = QB*z_rec[r] + QC*t[r]  (+QA on the diagonal when DIAG).
__device__ __forceinline__ void recomb_tile(f32x16& t,
                                            const u32x4& gh0, const u32x4& gl0,
                                            const u32x4& gh1, const u32x4& gl1,
                                            bool diag, int hi, int c) {
#pragma unroll
    for (int p = 0; p < 2; ++p) {
        const u32x4 gh = p ? gh1 : gh0;
        const u32x4 gl = p ? gl1 : gl0;
        const u32x2 rh0 = __builtin_amdgcn_permlane32_swap(gh[0], gh[2], false, false);
        const u32x2 rh1 = __builtin_amdgcn_permlane32_swap(gh[1], gh[3], false, false);
        const u32x2 rl0 = __builtin_amdgcn_permlane32_swap(gl[0], gl[2], false, false);
        const u32x2 rl1 = __builtin_amdgcn_permlane32_swap(gl[1], gl[3], false, false);
        // hdw[k] packs z[8p+2k] (lo16) and z[8p+2k+1] (hi16); same for ldw.
        const unsigned hdw[4] = {rh0[0], rh1[0], rh0[1], rh1[1]};
        const unsigned ldw[4] = {rl0[0], rl1[0], rl0[1], rl1[1]};
#pragma unroll
        for (int k = 0; k < 4; ++k) {
            const float zlo = __uint_as_float(hdw[k] << 16)
                            + __uint_as_float(ldw[k] << 16);
            const float zhi = __uint_as_float(hdw[k] & 0xFFFF0000u)
                            + __uint_as_float(ldw[k] & 0xFFFF0000u);
            const int r0 = 8*p + 2*k, r1 = r0 + 1;
            float w0 = QB * zlo + QC * t[r0];
            float w1 = QB * zhi + QC * t[r1];
            if (diag) {
                if (((r0 & 3) + 8*(r0 >> 2) + 4*hi) == c) w0 += QA;
                if (((r1 & 3) + 8*(r1 >> 2) + 4*hi) == c) w1 += QA;
            }
            t[r0] = w0; t[r1] = w1;
        }
    }
}

__global__ __launch_bounds__(64, 2)
void spd_rectified_kernel(const float* __restrict__ Xg_all,
                          float* __restrict__ out_all) {
    // Y0 parking: lane-private 16B slots, conflict-free. 16 KB/block ->
    // 8 blocks/CU = 128 KB <= 160 KB.
    __shared__ u32x4 park[16][64];

    const int lane = threadIdx.x;       // 64 threads = 1 wave
    const int c    = lane & 31;
    const int hi   = lane >> 5;

    const float* __restrict__ Xg = Xg_all + (size_t)blockIdx.x * 4096;
    float* __restrict__ Og = out_all + (size_t)blockIdx.x * 4096;

    // ---- load X in frag-shaped slices: row 32b+c, k = 16q+8hi+[0,8) ----
    float4 xv[2][4][2];
    float ss = 0.f;
#pragma unroll
    for (int b = 0; b < 2; ++b) {
        const float* xr = Xg + (32*b + c) * 64 + 8*hi;
#pragma unroll
        for (int q = 0; q < 4; ++q) {
            const float4 f0 = *reinterpret_cast<const float4*>(xr + 16*q);
            const float4 f1 = *reinterpret_cast<const float4*>(xr + 16*q + 4);
            xv[b][q][0] = f0; xv[b][q][1] = f1;
            ss += f0.x*f0.x + f0.y*f0.y + f0.z*f0.z + f0.w*f0.w;
            ss += f1.x*f1.x + f1.y*f1.y + f1.z*f1.z + f1.w*f1.w;
        }
    }
#pragma unroll
    for (int off = 32; off; off >>= 1) ss += __shfl_xor(ss, off, 64);
    const float ainv  = rsqrtf(ss + 1e-30f);
    const float alpha = ss * ainv;      // sqrt(ss)

    // ---- Y0 = X*ainv as frags; keep as iterate Y, park a copy in LDS ----
    u32x4 Yh[2][4], Yl[2][4];
#pragma unroll
    for (int b = 0; b < 2; ++b)
#pragma unroll
        for (int q = 0; q < 4; ++q) {
            const float4 f0 = xv[b][q][0], f1 = xv[b][q][1];
            unsigned h0, l0, h1, l1, h2, l2, h3, l3;
            split2(f0.x*ainv, f0.y*ainv, h0, l0);
            split2(f0.z*ainv, f0.w*ainv, h1, l1);
            split2(f1.x*ainv, f1.y*ainv, h2, l2);
            split2(f1.z*ainv, f1.w*ainv, h3, l3);
            Yh[b][q] = u32x4{h0, h1, h2, h3};
            Yl[b][q] = u32x4{l0, l1, l2, l3};
            park[b*4 + q][lane]     = Yh[b][q];
            park[8 + b*4 + q][lane] = Yl[b][q];
        }

    u32x4 Gh[2][4], Gl[2][4];           // scratch frag set (Z, then W)

    // ---- 4 quintic iterations: Y <- Y*(QA*I + QB*Y^2 + QC*Y^4) ----
#pragma unroll 1
    for (int it = 0; it < 4; ++it) {
        f32x16 z00, z01, z10, z11;
        matmul3(Yh, Yl, Yh, Yl, z00, z01, z10, z11);     // Z = Y^2
        CONV4(z00, z01, z10, z11, Gh, Gl);               // Z frags; z accs die
        f32x16 t00, t01, t10, t11;
        matmul3(Gh, Gl, Gh, Gl, t00, t01, t10, t11);     // T = Z^2
        // W = QA*I + QB*Z + QC*T, Z reconstructed from its frags (2^-17).
        recomb_tile(t00, Gh[0][0], Gl[0][0], Gh[0][1], Gl[0][1], true,  hi, c);
        recomb_tile(t01, Gh[1][0], Gl[1][0], Gh[1][1], Gl[1][1], false, hi, c);
        recomb_tile(t10, Gh[0][2], Gl[0][2], Gh[0][3], Gl[0][3], false, hi, c);
        recomb_tile(t11, Gh[1][2], Gl[1][2], Gh[1][3], Gl[1][3], true,  hi, c);
        CONV4(t00, t01, t10, t11, Gh, Gl);               // W frags over Z frags
        f32x16 y00, y01, y10, y11;
        matmul3(Yh, Yl, Gh, Gl, y00, y01, y10, y11);     // Ynew = Y*W
        CONV4(y00, y01, y10, y11, Yh, Yl);
    }

    // ---- 3 cubic iterations: Y <- Y*(1.5I - 0.5*Y^2) ----
#pragma unroll 1
    for (int it = 0; it < 3; ++it) {
        f32x16 z00, z01, z10, z11;
        matmul3(Yh, Yl, Yh, Yl, z00, z01, z10, z11);     // Z = Y^2
#pragma unroll
        for (int r = 0; r < 16; ++r) {                   // W = 1.5I - 0.5Z
            const int rw = (r & 3) + 8*(r >> 2) + 4*hi;
            float w;
            w = -0.5f*z00[r]; if (rw == c) w += 1.5f; z00[r] = w;
            w = -0.5f*z01[r];                         z01[r] = w;
            w = -0.5f*z10[r];                         z10[r] = w;
            w = -0.5f*z11[r]; if (rw == c) w += 1.5f; z11[r] = w;
        }
        CONV4(z00, z01, z10, z11, Gh, Gl);               // W frags
        f32x16 y00, y01, y10, y11;
        matmul3(Yh, Yl, Gh, Gl, y00, y01, y10, y11);     // Ynew = Y*W
        CONV4(y00, y01, y10, y11, Yh, Yl);
    }

    // ---- final: out = 0.5*alpha*(Y0 + Y0*S), S = Y ----
    u32x4 Ph[2][4], Pl[2][4];                            // unpark Y0
#pragma unroll
    for (int b = 0; b < 2; ++b)
#pragma unroll
        for (int q = 0; q < 4; ++q) {
            Ph[b][q] = park[b*4 + q][lane];
            Pl[b][q] = park[8 + b*4 + q][lane];
        }
    f32x16 c00, c01, c10, c11;
    matmul3(Ph, Pl, Yh, Yl, c00, c01, c10, c11);         // C = Y0*S
    const float hsc = 0.5f * alpha;

#define FINTILE(I, J, CC)                                                       \
    {                                                                           \
        const u32x2 sA0 = __builtin_amdgcn_permlane32_swap(Ph[J][2*I][0],  Ph[J][2*I][2],  false, false); \
        const u32x2 sA1 = __builtin_amdgcn_permlane32_swap(Ph[J][2*I][1],  Ph[J][2*I][3],  false, false); \
        const u32x2 sB0 = __builtin_amdgcn_permlane32_swap(Ph[J][2*I+1][0], Ph[J][2*I+1][2], false, false); \
        const u32x2 sB1 = __builtin_amdgcn_permlane32_swap(Ph[J][2*I+1][1], Ph[J][2*I+1][3], false, false); \
        const u32x2 uA0 = __builtin_amdgcn_permlane32_swap(Pl[J][2*I][0],  Pl[J][2*I][2],  false, false); \
        const u32x2 uA1 = __builtin_amdgcn_permlane32_swap(Pl[J][2*I][1],  Pl[J][2*I][3],  false, false); \
        const u32x2 uB0 = __builtin_amdgcn_permlane32_swap(Pl[J][2*I+1][0], Pl[J][2*I+1][2], false, false); \
        const u32x2 uB1 = __builtin_amdgcn_permlane32_swap(Pl[J][2*I+1][1], Pl[J][2*I+1][3], false, false); \
        _Pragma("unroll")                                                       \
        for (int m = 0; m < 4; ++m) {                                           \
            const int sel = m & 1;                                              \
            const unsigned hd0 = (m >> 1) ? sB0[sel] : sA0[sel];                \
            const unsigned hd1 = (m >> 1) ? sB1[sel] : sA1[sel];                \
            const unsigned ld0 = (m >> 1) ? uB0[sel] : uA0[sel];                \
            const unsigned ld1 = (m >> 1) ? uB1[sel] : uA1[sel];                \
            _Pragma("unroll")                                                   \
            for (int j = 0; j < 4; ++j) {                                       \
                const unsigned hd = (j >> 1) ? hd1 : hd0;                       \
                const unsigned ld = (j >> 1) ? ld1 : ld0;                       \
                const float fh = __uint_as_float((j & 1) ? (hd & 0xFFFF0000u) : (hd << 16)); \
                const float fl = __uint_as_float((j & 1) ? (ld & 0xFFFF0000u) : (ld << 16)); \
                const float o  = hsc * ((fh + fl) + CC[4*m + j]);               \
                Og[(32*(I) + 8*m + 4*hi + j) * 64 + 32*(J) + c] = o;            \
            }                                                                   \
        }                                                                       \
    }

    FINTILE(0, 0, c00)
    FINTILE(0, 1, c01)
    FINTILE(1, 0, c10)
    FINTILE(1, 1, c11)
#undef FINTILE
}

extern "C" void kernel_launch(void* const* d_in, const int* in_sizes, int n_in,
                              void* d_out, int out_size, void* d_ws, size_t ws_size,
                              hipStream_t stream) {
    const float* x = (const float*)d_in[0];
    float* out = (float*)d_out;
    const int nmat = in_sizes[0] >> 12;
    spd_rectified_kernel<<<nmat, 64, 0, stream>>>(x, out);
}